// Round 1
// baseline (835.964 us; speedup 1.0000x reference)
//
#include <hip/hip_runtime.h>
#include <math.h>

#define NPIX (480*640)
#define GRID_VOX 800000          // 100*100*80
#define MDIM 960
#define MPIX (MDIM*MDIM)

// workspace layout (floats)
#define GRID_OFF 0               // 6 * 800000
#define SM_OFF   4800000         // 7 planes * 10000: [fp, exp, cat0..cat4]
#define SCAL_OFF 4870000         // [ct, sn, sx, sy, ks0..ks3]
#define WS_ZERO_FLOATS 4870016

// output layout (floats)
#define OUT_FPMAP 0
#define OUT_MAP   10000
#define OUT_POSE  (10000 + 9*MPIX)

__global__ void pose_kernel(const float* pose_obs, const float* poses_last,
                            float* scal, float* out_pose) {
    if (threadIdx.x == 0) {
        const float DEGc = 57.29577951308232f;
        float th = poses_last[2] / DEGc;
        float s = sinf(th), c = cosf(th);
        float ny = poses_last[1] + pose_obs[0]*s + pose_obs[1]*c;
        float nx = poses_last[0] + pose_obs[0]*c - pose_obs[1]*s;
        float nt = poses_last[2] + pose_obs[2]*DEGc;
        nt = fmodf(nt - 180.0f, 360.0f) + 180.0f;
        nt = fmodf(nt + 180.0f, 360.0f) - 180.0f;
        out_pose[0] = nx; out_pose[1] = ny; out_pose[2] = nt;
        out_pose[3] = nx; out_pose[4] = ny; out_pose[5] = nt;
        float sx = -((nx*100.0f)/5.0f - 480.0f)/480.0f;
        float sy = -((ny*100.0f)/5.0f - 480.0f)/480.0f;
        float sth = ((90.0f - nt) * 3.14159265358979323846f) / 180.0f;
        scal[0] = cosf(sth);
        scal[1] = sinf(sth);
        scal[2] = sx;
        scal[3] = sy;
    }
}

__global__ void ks_kernel(const float* __restrict__ obs, float* scal) {
    int tid = blockIdx.x*blockDim.x + threadIdx.x;
    int stride = gridDim.x*blockDim.x;
    float m0 = 0.0f, m1 = 0.0f, m2 = 0.0f, m3 = 0.0f;  // obs values are >= 0
    for (int p = tid; p < NPIX; p += stride) {
        m0 = fmaxf(m0, obs[4*NPIX + p]);
        m1 = fmaxf(m1, obs[5*NPIX + p]);
        m2 = fmaxf(m2, obs[6*NPIX + p]);
        m3 = fmaxf(m3, obs[7*NPIX + p]);
    }
    #pragma unroll
    for (int off = 32; off > 0; off >>= 1) {
        m0 = fmaxf(m0, __shfl_down(m0, off, 64));
        m1 = fmaxf(m1, __shfl_down(m1, off, 64));
        m2 = fmaxf(m2, __shfl_down(m2, off, 64));
        m3 = fmaxf(m3, __shfl_down(m3, off, 64));
    }
    if ((threadIdx.x & 63) == 0) {
        // nonneg float bits compare like ints
        atomicMax((int*)&scal[4], __float_as_int(m0));
        atomicMax((int*)&scal[5], __float_as_int(m1));
        atomicMax((int*)&scal[6], __float_as_int(m2));
        atomicMax((int*)&scal[7], __float_as_int(m3));
    }
}

__global__ __launch_bounds__(256) void splat_kernel(const float* __restrict__ obs,
                                                    float* __restrict__ grid, float fcam) {
    int pix = blockIdx.x*blockDim.x + threadIdx.x;
    if (pix >= NPIX) return;
    int i = pix / 640, j = pix - i*640;
    float d = obs[3*NPIX + pix];
    float X = ((float)j - 319.5f) * d / fcam + 250.0f;
    float Z = ((float)(479 - i) - 239.5f) * d / fcam + 88.0f;
    float xs = ((X/5.0f - 50.0f)/100.0f)*2.0f;
    float ys = ((d/5.0f - 50.0f)/100.0f)*2.0f;
    float zs = ((Z/5.0f - 32.0f)/80.0f)*2.0f;
    float pos0 = (xs*100.0f)/2.0f + 50.0f;
    float pos1 = (ys*100.0f)/2.0f + 50.0f;
    float pos2 = (zs*80.0f)/2.0f + 40.0f;
    float f0 = floorf(pos0), f1 = floorf(pos1), f2 = floorf(pos2);
    float feat[6];
    feat[0] = 1.0f;
    feat[1] = obs[4*NPIX + pix];
    feat[2] = obs[5*NPIX + pix];
    feat[3] = obs[6*NPIX + pix];
    feat[4] = obs[7*NPIX + pix];
    feat[5] = obs[8*NPIX + pix];
    #pragma unroll
    for (int c0 = 0; c0 <= 1; c0++) {
        float p0 = f0 + (float)c0;
        if (!(p0 > 0.0f && p0 < 100.0f)) continue;
        float w0 = 1.0f - fabsf(pos0 - p0);
        #pragma unroll
        for (int c1 = 0; c1 <= 1; c1++) {
            float p1 = f1 + (float)c1;
            if (!(p1 > 0.0f && p1 < 100.0f)) continue;
            float w01 = w0 * (1.0f - fabsf(pos1 - p1));
            #pragma unroll
            for (int c2 = 0; c2 <= 1; c2++) {
                float p2 = f2 + (float)c2;
                if (!(p2 > 0.0f && p2 < 80.0f)) continue;
                float w = w01 * (1.0f - fabsf(pos2 - p2));
                int idx = (((int)p0)*100 + (int)p1)*80 + (int)p2;
                #pragma unroll
                for (int ff = 0; ff < 6; ff++)
                    atomicAdd(&grid[ff*GRID_VOX + idx], feat[ff]*w);
            }
        }
    }
}

__global__ void reduce_kernel(const float* __restrict__ grid,
                              float* __restrict__ sm, float* __restrict__ out_fp) {
    int t = blockIdx.x*blockDim.x + threadIdx.x;
    if (t >= 10000) return;
    int r = t / 100, c = t - r*100;      // r = Y index, c = X index
    int base = (c*100 + r)*80;           // grid flat = (X*100 + Y)*80 + z
    float ahp[6];
    #pragma unroll
    for (int ff = 0; ff < 6; ff++) {
        float s = 0.0f;
        for (int z = 13; z < 25; z++) s += rintf(grid[ff*GRID_VOX + base + z]);
        ahp[ff] = s;
    }
    float all0 = 0.0f;
    for (int z = 0; z < 80; z++) all0 += rintf(grid[base + z]);
    float fp = fminf(fmaxf(ahp[0], 0.0f), 1.0f);
    float ex = fminf(fmaxf(all0, 0.0f), 1.0f);
    sm[0*10000 + t] = fp;
    sm[1*10000 + t] = ex;
    #pragma unroll
    for (int k = 0; k < 5; k++)
        sm[(2+k)*10000 + t] = fminf(fmaxf(ahp[k+1]/5.0f, 0.0f), 1.0f);
    out_fp[t] = fp;
}

// bilinear sample of the (implicit, mostly-zero) agent_view at normalized coords,
// accumulating the 7 nonzero channels [0,1,4,5,6,7,8] from the small maps.
__device__ __forceinline__ void sample_agent(float gxv, float gyv,
                                             float ct, float sn,
                                             const float* __restrict__ sm,
                                             float rot[7]) {
    float u = ct*gxv - sn*gyv;
    float v = sn*gxv + ct*gyv;
    float xim = ((u + 1.0f)*0.5f)*959.0f;
    float yim = ((v + 1.0f)*0.5f)*959.0f;
    float x0 = floorf(xim), y0 = floorf(yim);
    #pragma unroll
    for (int ty = 0; ty <= 1; ty++) {
        float yy = y0 + (float)ty;
        if (yy < 480.0f || yy >= 580.0f) continue;   // region rows [480,580) ⊂ [0,959]
        float wy = 1.0f - fabsf(yim - yy);
        int yi = (int)yy - 480;
        #pragma unroll
        for (int tx = 0; tx <= 1; tx++) {
            float xx = x0 + (float)tx;
            if (xx < 430.0f || xx >= 530.0f) continue;  // region cols [430,530)
            float w = (1.0f - fabsf(xim - xx)) * wy;
            int o = yi*100 + ((int)xx - 430);
            #pragma unroll
            for (int k = 0; k < 7; k++) rot[k] += sm[k*10000 + o] * w;
        }
    }
}

__global__ __launch_bounds__(256) void final_kernel(const float* __restrict__ maps_last,
                                                    const float* __restrict__ sm,
                                                    const float* __restrict__ scal,
                                                    float* __restrict__ out_map) {
    int t = blockIdx.x*blockDim.x + threadIdx.x;
    if (t >= MPIX) return;
    int y = t / MDIM, x = t - y*MDIM;
    float ct = scal[0], sn = scal[1], sx = scal[2], sy = scal[3];
    float ks0 = scal[4], ks1 = scal[5], ks2 = scal[6], ks3 = scal[7];
    const float step = 2.0f/959.0f;
    float gxv = (float)x*step - 1.0f;
    float gyv = (float)y*step - 1.0f;
    float u = gxv + sx, v = gyv + sy;
    float xim = ((u + 1.0f)*0.5f)*959.0f;
    float yim = ((v + 1.0f)*0.5f)*959.0f;
    float x0 = floorf(xim), y0 = floorf(yim);
    float ts[7] = {0,0,0,0,0,0,0};
    #pragma unroll
    for (int ty = 0; ty <= 1; ty++) {
        float yy = y0 + (float)ty;
        if (yy < 0.0f || yy > 959.0f) continue;
        float wy = 1.0f - fabsf(yim - yy);
        #pragma unroll
        for (int tx = 0; tx <= 1; tx++) {
            float xx = x0 + (float)tx;
            if (xx < 0.0f || xx > 959.0f) continue;
            float w = (1.0f - fabsf(xim - xx)) * wy;
            // recompute rotated(yy, xx) exactly (bit-identical to materializing it)
            float rot[7] = {0,0,0,0,0,0,0};
            float gx1 = xx*step - 1.0f;
            float gy1 = yy*step - 1.0f;
            sample_agent(gx1, gy1, ct, sn, sm, rot);
            #pragma unroll
            for (int k = 0; k < 7; k++) ts[k] += rot[k]*w;
        }
    }
    int o = t;
    float ml;
    ml = maps_last[0*MPIX + o]; out_map[0*MPIX + o] = fmaxf(ml, ts[0]);
    ml = maps_last[1*MPIX + o]; out_map[1*MPIX + o] = fmaxf(ml, ts[1]);
    ml = maps_last[2*MPIX + o]; out_map[2*MPIX + o] = fmaxf(ml, 0.0f);
    ml = maps_last[3*MPIX + o]; out_map[3*MPIX + o] = fmaxf(ml, 0.0f);
    float t4 = ts[2]; t4 = (t4 > 0.0f) ? ks0 : t4;
    ml = maps_last[4*MPIX + o]; out_map[4*MPIX + o] = fmaxf(ml, t4);
    float t5 = ts[3]; t5 = (t5 > 0.0f) ? ks1 : t5;
    ml = maps_last[5*MPIX + o]; out_map[5*MPIX + o] = fmaxf(ml, t5);
    float t6 = ts[4]; t6 = (t6 > 0.0f) ? ks2 : t6;
    ml = maps_last[6*MPIX + o]; out_map[6*MPIX + o] = fmaxf(ml, t6);
    float t7 = ts[5]; t7 = (t7 > 0.0f) ? ks3 : t7;
    ml = maps_last[7*MPIX + o]; out_map[7*MPIX + o] = fmaxf(ml, t7);
    ml = maps_last[8*MPIX + o]; out_map[8*MPIX + o] = fmaxf(ml, ts[6]);
}

extern "C" void kernel_launch(void* const* d_in, const int* in_sizes, int n_in,
                              void* d_out, int out_size, void* d_ws, size_t ws_size,
                              hipStream_t stream) {
    const float* obs        = (const float*)d_in[0];
    const float* pose_obs   = (const float*)d_in[1];
    const float* maps_last  = (const float*)d_in[2];
    const float* poses_last = (const float*)d_in[3];
    float* out = (float*)d_out;
    float* ws  = (float*)d_ws;

    // zero the voxel grid + small maps + scalars (ws is poisoned 0xAA each launch)
    hipMemsetAsync(d_ws, 0, (size_t)WS_ZERO_FLOATS * sizeof(float), stream);

    // f = w/2 / tan(deg2rad(FOV/2)), computed on host in double like numpy
    float fcam = (float)(320.0 / tan(39.5 * M_PI / 180.0));

    pose_kernel<<<1, 64, 0, stream>>>(pose_obs, poses_last, ws + SCAL_OFF, out + OUT_POSE);
    ks_kernel<<<128, 256, 0, stream>>>(obs, ws + SCAL_OFF);
    splat_kernel<<<(NPIX + 255)/256, 256, 0, stream>>>(obs, ws + GRID_OFF, fcam);
    reduce_kernel<<<(10000 + 255)/256, 256, 0, stream>>>(ws + GRID_OFF, ws + SM_OFF, out + OUT_FPMAP);
    final_kernel<<<(MPIX + 255)/256, 256, 0, stream>>>(maps_last, ws + SM_OFF, ws + SCAL_OFF, out + OUT_MAP);
}

// Round 2
// 506.531 us; speedup vs baseline: 1.6504x; 1.6504x over previous
//
#include <hip/hip_runtime.h>
#include <math.h>

#define NPIX (480*640)
#define NVOX 800000              // 100*100*80 voxels
#define MDIM 960
#define MPIX (MDIM*MDIM)
#define FIX_SH 20
#define FIX_SC 1048576.0f        // 2^20 fixed-point scale
#define SM_FLOATS 70000          // 7 planes * 10000
#define SCAL_FLOATS 16

// output layout (floats)
#define OUT_FPMAP 0
#define OUT_MAP   10000
#define OUT_POSE  (10000 + 9*MPIX)

__global__ void pose_kernel(const float* pose_obs, const float* poses_last,
                            float* scal, float* out_pose) {
    if (threadIdx.x == 0) {
        const float DEGc = 57.29577951308232f;
        float th = poses_last[2] / DEGc;
        float s = sinf(th), c = cosf(th);
        float ny = poses_last[1] + pose_obs[0]*s + pose_obs[1]*c;
        float nx = poses_last[0] + pose_obs[0]*c - pose_obs[1]*s;
        float nt = poses_last[2] + pose_obs[2]*DEGc;
        nt = fmodf(nt - 180.0f, 360.0f) + 180.0f;
        nt = fmodf(nt + 180.0f, 360.0f) - 180.0f;
        out_pose[0] = nx; out_pose[1] = ny; out_pose[2] = nt;
        out_pose[3] = nx; out_pose[4] = ny; out_pose[5] = nt;
        float sx = -((nx*100.0f)/5.0f - 480.0f)/480.0f;
        float sy = -((ny*100.0f)/5.0f - 480.0f)/480.0f;
        float sth = ((90.0f - nt) * 3.14159265358979323846f) / 180.0f;
        scal[0] = cosf(sth);
        scal[1] = sinf(sth);
        scal[2] = sx;
        scal[3] = sy;
    }
}

__global__ void ks_kernel(const float* __restrict__ obs, float* scal) {
    int tid = blockIdx.x*blockDim.x + threadIdx.x;
    int stride = gridDim.x*blockDim.x;
    float m0 = 0.0f, m1 = 0.0f, m2 = 0.0f, m3 = 0.0f;  // obs values are >= 0
    for (int p = tid; p < NPIX; p += stride) {
        m0 = fmaxf(m0, obs[4*NPIX + p]);
        m1 = fmaxf(m1, obs[5*NPIX + p]);
        m2 = fmaxf(m2, obs[6*NPIX + p]);
        m3 = fmaxf(m3, obs[7*NPIX + p]);
    }
    #pragma unroll
    for (int off = 32; off > 0; off >>= 1) {
        m0 = fmaxf(m0, __shfl_down(m0, off, 64));
        m1 = fmaxf(m1, __shfl_down(m1, off, 64));
        m2 = fmaxf(m2, __shfl_down(m2, off, 64));
        m3 = fmaxf(m3, __shfl_down(m3, off, 64));
    }
    if ((threadIdx.x & 63) == 0) {
        atomicMax((int*)&scal[4], __float_as_int(m0));
        atomicMax((int*)&scal[5], __float_as_int(m1));
        atomicMax((int*)&scal[6], __float_as_int(m2));
        atomicMax((int*)&scal[7], __float_as_int(m3));
    }
}

__device__ __forceinline__ unsigned long long pack2(float a, float b) {
    unsigned int la = __float2uint_rn(a * FIX_SC);
    unsigned int lb = __float2uint_rn(b * FIX_SC);
    return (unsigned long long)la | ((unsigned long long)lb << 32);
}

__global__ __launch_bounds__(256) void splat_kernel(const float* __restrict__ obs,
                                                    unsigned long long* __restrict__ grid,
                                                    float fcam, int vstride) {
    int pix = blockIdx.x*blockDim.x + threadIdx.x;
    if (pix >= NPIX) return;
    int i = pix / 640, j = pix - i*640;
    float d = obs[3*NPIX + pix];
    float X = ((float)j - 319.5f) * d / fcam + 250.0f;
    float Z = ((float)(479 - i) - 239.5f) * d / fcam + 88.0f;
    float xs = ((X/5.0f - 50.0f)/100.0f)*2.0f;
    float ys = ((d/5.0f - 50.0f)/100.0f)*2.0f;
    float zs = ((Z/5.0f - 32.0f)/80.0f)*2.0f;
    float pos0 = (xs*100.0f)/2.0f + 50.0f;
    float pos1 = (ys*100.0f)/2.0f + 50.0f;
    float pos2 = (zs*80.0f)/2.0f + 40.0f;
    float f0 = floorf(pos0), f1 = floorf(pos1), f2 = floorf(pos2);
    float ft1 = obs[4*NPIX + pix];
    float ft2 = obs[5*NPIX + pix];
    float ft3 = obs[6*NPIX + pix];
    float ft4 = obs[7*NPIX + pix];
    float ft5 = obs[8*NPIX + pix];
    #pragma unroll
    for (int c0 = 0; c0 <= 1; c0++) {
        float p0 = f0 + (float)c0;
        if (!(p0 > 0.0f && p0 < 100.0f)) continue;
        float w0 = 1.0f - fabsf(pos0 - p0);
        #pragma unroll
        for (int c1 = 0; c1 <= 1; c1++) {
            float p1 = f1 + (float)c1;
            if (!(p1 > 0.0f && p1 < 100.0f)) continue;
            float w01 = w0 * (1.0f - fabsf(pos1 - p1));
            #pragma unroll
            for (int c2 = 0; c2 <= 1; c2++) {
                float p2 = f2 + (float)c2;
                if (!(p2 > 0.0f && p2 < 80.0f)) continue;
                float w = w01 * (1.0f - fabsf(pos2 - p2));
                int idx = (((int)p0)*100 + (int)p1)*80 + (int)p2;
                unsigned long long* g = grid + (size_t)idx * vstride;
                atomicAdd(&g[0], pack2(w,      w*ft1));
                atomicAdd(&g[1], pack2(w*ft2,  w*ft3));
                atomicAdd(&g[2], pack2(w*ft4,  w*ft5));
            }
        }
    }
}

__device__ __forceinline__ unsigned int rnd_lo(unsigned long long g) {
    return (unsigned int)(((g & 0xFFFFFFFFull) + (1ull << (FIX_SH-1))) >> FIX_SH);
}
__device__ __forceinline__ unsigned int rnd_hi(unsigned long long g) {
    return (unsigned int)(((g >> 32) + (1ull << (FIX_SH-1))) >> FIX_SH);
}

__global__ void reduce_kernel(const unsigned long long* __restrict__ grid,
                              float* __restrict__ sm, float* __restrict__ out_fp,
                              int vstride) {
    int t = blockIdx.x*blockDim.x + threadIdx.x;
    if (t >= 10000) return;
    int r = t / 100, c = t - r*100;      // r = Y index, c = X index
    int vbase = (c*100 + r)*80;          // voxel flat = (X*100 + Y)*80 + z
    unsigned int ahp[6] = {0,0,0,0,0,0};
    unsigned int all0 = 0;
    for (int z = 0; z < 80; z++) {
        const unsigned long long* g = grid + (size_t)(vbase + z) * vstride;
        unsigned long long g0 = g[0];
        unsigned int cnt0 = rnd_lo(g0);
        all0 += cnt0;
        if (z >= 13 && z < 25) {
            unsigned long long g1 = g[1];
            unsigned long long g2 = g[2];
            ahp[0] += cnt0;
            ahp[1] += rnd_hi(g0);
            ahp[2] += rnd_lo(g1);
            ahp[3] += rnd_hi(g1);
            ahp[4] += rnd_lo(g2);
            ahp[5] += rnd_hi(g2);
        }
    }
    float fp = fminf((float)ahp[0], 1.0f);
    float ex = fminf((float)all0, 1.0f);
    sm[0*10000 + t] = fp;
    sm[1*10000 + t] = ex;
    #pragma unroll
    for (int k = 0; k < 5; k++)
        sm[(2+k)*10000 + t] = fminf((float)ahp[k+1]/5.0f, 1.0f);
    out_fp[t] = fp;
}

// bilinear sample of the (implicit, mostly-zero) agent_view at normalized coords,
// accumulating the 7 nonzero channels [0,1,4,5,6,7,8] from the small maps.
__device__ __forceinline__ void sample_agent(float gxv, float gyv,
                                             float ct, float sn,
                                             const float* __restrict__ sm,
                                             float rot[7]) {
    float u = ct*gxv - sn*gyv;
    float v = sn*gxv + ct*gyv;
    float xim = ((u + 1.0f)*0.5f)*959.0f;
    float yim = ((v + 1.0f)*0.5f)*959.0f;
    float x0 = floorf(xim), y0 = floorf(yim);
    #pragma unroll
    for (int ty = 0; ty <= 1; ty++) {
        float yy = y0 + (float)ty;
        if (yy < 480.0f || yy >= 580.0f) continue;   // region rows [480,580)
        float wy = 1.0f - fabsf(yim - yy);
        int yi = (int)yy - 480;
        #pragma unroll
        for (int tx = 0; tx <= 1; tx++) {
            float xx = x0 + (float)tx;
            if (xx < 430.0f || xx >= 530.0f) continue;  // region cols [430,530)
            float w = (1.0f - fabsf(xim - xx)) * wy;
            int o = yi*100 + ((int)xx - 430);
            #pragma unroll
            for (int k = 0; k < 7; k++) rot[k] += sm[k*10000 + o] * w;
        }
    }
}

__global__ __launch_bounds__(256) void final_kernel(const float* __restrict__ maps_last,
                                                    const float* __restrict__ sm,
                                                    const float* __restrict__ scal,
                                                    float* __restrict__ out_map) {
    int t = blockIdx.x*blockDim.x + threadIdx.x;
    if (t >= MPIX) return;
    int y = t / MDIM, x = t - y*MDIM;
    float ct = scal[0], sn = scal[1], sx = scal[2], sy = scal[3];
    float ks0 = scal[4], ks1 = scal[5], ks2 = scal[6], ks3 = scal[7];
    const float step = 2.0f/959.0f;
    float gxv = (float)x*step - 1.0f;
    float gyv = (float)y*step - 1.0f;
    float u = gxv + sx, v = gyv + sy;
    float xim = ((u + 1.0f)*0.5f)*959.0f;
    float yim = ((v + 1.0f)*0.5f)*959.0f;
    float x0 = floorf(xim), y0 = floorf(yim);
    float ts[7] = {0,0,0,0,0,0,0};
    #pragma unroll
    for (int ty = 0; ty <= 1; ty++) {
        float yy = y0 + (float)ty;
        if (yy < 0.0f || yy > 959.0f) continue;
        float wy = 1.0f - fabsf(yim - yy);
        #pragma unroll
        for (int tx = 0; tx <= 1; tx++) {
            float xx = x0 + (float)tx;
            if (xx < 0.0f || xx > 959.0f) continue;
            float w = (1.0f - fabsf(xim - xx)) * wy;
            // recompute rotated(yy, xx) exactly (bit-identical to materializing it)
            float rot[7] = {0,0,0,0,0,0,0};
            float gx1 = xx*step - 1.0f;
            float gy1 = yy*step - 1.0f;
            sample_agent(gx1, gy1, ct, sn, sm, rot);
            #pragma unroll
            for (int k = 0; k < 7; k++) ts[k] += rot[k]*w;
        }
    }
    int o = t;
    float ml;
    ml = maps_last[0*MPIX + o]; out_map[0*MPIX + o] = fmaxf(ml, ts[0]);
    ml = maps_last[1*MPIX + o]; out_map[1*MPIX + o] = fmaxf(ml, ts[1]);
    ml = maps_last[2*MPIX + o]; out_map[2*MPIX + o] = fmaxf(ml, 0.0f);
    ml = maps_last[3*MPIX + o]; out_map[3*MPIX + o] = fmaxf(ml, 0.0f);
    float t4 = ts[2]; t4 = (t4 > 0.0f) ? ks0 : t4;
    ml = maps_last[4*MPIX + o]; out_map[4*MPIX + o] = fmaxf(ml, t4);
    float t5 = ts[3]; t5 = (t5 > 0.0f) ? ks1 : t5;
    ml = maps_last[5*MPIX + o]; out_map[5*MPIX + o] = fmaxf(ml, t5);
    float t6 = ts[4]; t6 = (t6 > 0.0f) ? ks2 : t6;
    ml = maps_last[6*MPIX + o]; out_map[6*MPIX + o] = fmaxf(ml, t6);
    float t7 = ts[5]; t7 = (t7 > 0.0f) ? ks3 : t7;
    ml = maps_last[7*MPIX + o]; out_map[7*MPIX + o] = fmaxf(ml, t7);
    ml = maps_last[8*MPIX + o]; out_map[8*MPIX + o] = fmaxf(ml, ts[6]);
}

extern "C" void kernel_launch(void* const* d_in, const int* in_sizes, int n_in,
                              void* d_out, int out_size, void* d_ws, size_t ws_size,
                              hipStream_t stream) {
    const float* obs        = (const float*)d_in[0];
    const float* pose_obs   = (const float*)d_in[1];
    const float* maps_last  = (const float*)d_in[2];
    const float* poses_last = (const float*)d_in[3];
    float* out = (float*)d_out;

    // pick voxel stride: 4 u64 (32B-aligned, 1 sector/corner) if ws allows, else 3
    size_t need4 = (size_t)NVOX*4*8 + (size_t)(SM_FLOATS + SCAL_FLOATS)*4;
    int vstride = (ws_size >= need4) ? 4 : 3;
    size_t grid_bytes = (size_t)NVOX * vstride * 8;

    unsigned long long* grid = (unsigned long long*)d_ws;
    float* sm   = (float*)((char*)d_ws + grid_bytes);
    float* scal = sm + SM_FLOATS;

    // zero grid + small maps + scalars (ws is poisoned 0xAA each launch)
    hipMemsetAsync(d_ws, 0, grid_bytes + (size_t)(SM_FLOATS + SCAL_FLOATS)*4, stream);

    float fcam = (float)(320.0 / tan(39.5 * M_PI / 180.0));

    pose_kernel<<<1, 64, 0, stream>>>(pose_obs, poses_last, scal, out + OUT_POSE);
    ks_kernel<<<128, 256, 0, stream>>>(obs, scal);
    splat_kernel<<<(NPIX + 255)/256, 256, 0, stream>>>(obs, grid, fcam, vstride);
    reduce_kernel<<<(10000 + 255)/256, 256, 0, stream>>>(grid, sm, out + OUT_FPMAP, vstride);
    final_kernel<<<(MPIX + 255)/256, 256, 0, stream>>>(maps_last, sm, scal, out + OUT_MAP);
}